// Round 1
// baseline (739.277 us; speedup 1.0000x reference)
//
#include <hip/hip_runtime.h>
#include <hip/hip_bf16.h>

typedef __attribute__((ext_vector_type(8))) short bf16x8;
typedef __attribute__((ext_vector_type(16))) float f32x16;
typedef unsigned short ushort_t;
typedef unsigned int uint_t;

#define N_NODES 16384
#define HD 128
#define NOUT 384
#define BT_K 16640            // 16384 + 128 + 128

static __device__ __forceinline__ ushort_t f2bf(float f) {
  __hip_bfloat16 b = __float2bfloat16(f);
  return *reinterpret_cast<ushort_t*>(&b);
}

// ---------------- prep 1: A (16384 x 384 f32, k-major) -> Bt (384 x 16640 bf16) ----------------
__global__ void prep_bt(const float* __restrict__ A, ushort_t* __restrict__ Bt) {
  __shared__ float sm[64][65];
  const int kt = blockIdx.x;          // 0..255
  const int nt = blockIdx.y;          // 0..5
  const int t = threadIdx.x;
  const int tx = t & 63, ty = t >> 6;
  const int k0 = kt * 64, n0 = nt * 64;
#pragma unroll
  for (int s = 0; s < 16; ++s) {
    int kk = ty + s * 4;
    sm[kk][tx] = A[(size_t)(k0 + kk) * NOUT + n0 + tx];
  }
  __syncthreads();
#pragma unroll
  for (int s = 0; s < 16; ++s) {
    int nn = ty + s * 4;
    Bt[(size_t)(n0 + nn) * BT_K + k0 + tx] = f2bf(sm[tx][nn]);
  }
}

// ---------------- prep 2: U1,U2 (384x128) appended to Bt rows ----------------
__global__ void prep_u(const float* __restrict__ U1, const float* __restrict__ U2,
                       ushort_t* __restrict__ Bt) {
  int idx = blockIdx.x * 256 + threadIdx.x;   // 0..49151
  if (idx < NOUT * HD) {
    int n = idx >> 7, i = idx & 127;
    Bt[(size_t)n * BT_K + 16384 + i] = f2bf(U1[idx]);
    Bt[(size_t)n * BT_K + 16512 + i] = f2bf(U2[idx]);
  }
}

// ---------------- prep 3: neighbour_h -> h1_bf, h2_bf (m-major), h1t (i-major) ----------------
__global__ void prep_h(const float* __restrict__ nh, ushort_t* __restrict__ h1,
                       ushort_t* __restrict__ h2, ushort_t* __restrict__ h1t) {
  __shared__ float sm[64][65];
  const int mt = blockIdx.x;          // 0..255
  const int jt = blockIdx.y;          // 0..1
  const int t = threadIdx.x;
  const int tx = t & 63, ty = t >> 6;
  const int m0 = mt * 64, j0 = jt * 64;
#pragma unroll
  for (int s = 0; s < 16; ++s) {
    int mm = ty + s * 4;
    float f1 = nh[(size_t)(m0 + mm) * 256 + j0 + tx];
    float f2 = nh[(size_t)(m0 + mm) * 256 + 128 + j0 + tx];
    h1[(size_t)(m0 + mm) * HD + j0 + tx] = f2bf(f1);
    h2[(size_t)(m0 + mm) * HD + j0 + tx] = f2bf(f2);
    sm[mm][tx] = f1;
  }
  __syncthreads();
#pragma unroll
  for (int s = 0; s < 16; ++s) {
    int jj = ty + s * 4;
    h1t[(size_t)(j0 + jj) * N_NODES + m0 + tx] = f2bf(sm[tx][jj]);
  }
}

// ---------------- main GEMM: out[m][n] = sum_k X[m,k] * Bt[n,k] (+bias) ----------------
// X[m, i*128+j] = h1[m,i]*h2[m,j] for i<128; X[m,16384+i]=h1[m,i]; X[m,16512+j]=h2[m,j]
__global__ __launch_bounds__(256, 2)
void gemm_kernel(const ushort_t* __restrict__ Bt, const ushort_t* __restrict__ h1bf,
                 const ushort_t* __restrict__ h2bf, const ushort_t* __restrict__ h1t,
                 const float* __restrict__ u2b, float* __restrict__ out) {
  __shared__ short bsh[128 * 136];   // B tile [n][k], padded stride 136 (conflict-free)
  const int tid = threadIdx.x;
  const int bid = blockIdx.x;
  const int Nt = bid % 3, Mt = bid / 3;
  const int n0 = Nt * 128, m0 = Mt * 128;
  const int lane = tid & 63, wv = tid >> 6;
  const int l31 = lane & 31, oct = lane >> 5;
  const int wm = wv >> 1, wn = wv & 1;           // 2x2 wave grid
  const int mbase = m0 + wm * 64;
  const int nbase_l = wn * 64;

  // resident h2 A-fragments: rows mbase+ms*32+l31, k = c*16 + oct*8 + [0..8)
  bf16x8 h2f[2][8];
#pragma unroll
  for (int ms = 0; ms < 2; ++ms) {
    const ushort_t* hp = h2bf + (size_t)(mbase + ms * 32 + l31) * HD + oct * 8;
#pragma unroll
    for (int c = 0; c < 8; ++c)
      h2f[ms][c] = *reinterpret_cast<const bf16x8*>(hp + c * 16);
  }

  f32x16 acc[2][2];
#pragma unroll
  for (int ms = 0; ms < 2; ++ms)
#pragma unroll
    for (int ns = 0; ns < 2; ++ns)
      acc[ms][ns] = (f32x16)(0.0f);

  uint4 breg[8];
  const char* btbase = reinterpret_cast<const char*>(Bt);
  const int prow = ((tid >> 4));       // base row within 16-row group
  const int poff = (tid & 15);

  auto load_breg = [&](int i) {
#pragma unroll
    for (int l = 0; l < 8; ++l) {
      int row = prow + 16 * l;
      breg[l] = *reinterpret_cast<const uint4*>(
          btbase + (size_t)(n0 + row) * (BT_K * 2) + (size_t)i * 256 + poff * 16);
    }
  };
  load_breg(0);

  for (int i = 0; i < 130; ++i) {
    // stage prefetched B tile into LDS (padded)
#pragma unroll
    for (int l = 0; l < 8; ++l) {
      int row = prow + 16 * l;
      *reinterpret_cast<uint4*>(&bsh[row * 136 + poff * 8]) = breg[l];
    }
    __syncthreads();
    if (i < 129) load_breg(i + 1);   // prefetch next tile: in flight across compute

    if (i < 128) {
      uint_t h1u[2];
#pragma unroll
      for (int ms = 0; ms < 2; ++ms) {
        ushort_t hv = h1t[(size_t)i * N_NODES + mbase + ms * 32 + l31];
        h1u[ms] = (uint_t)hv * 0x10001u;   // broadcast to bf16x2
      }
#pragma unroll
      for (int c = 0; c < 8; ++c) {
        bf16x8 b0 = *reinterpret_cast<const bf16x8*>(&bsh[(nbase_l + l31) * 136 + c * 16 + oct * 8]);
        bf16x8 b1 = *reinterpret_cast<const bf16x8*>(&bsh[(nbase_l + 32 + l31) * 136 + c * 16 + oct * 8]);
#pragma unroll
        for (int ms = 0; ms < 2; ++ms) {
          union { bf16x8 v; uint_t u[4]; } av, hv2;
          hv2.v = h2f[ms][c];
          __hip_bfloat162 hb = *reinterpret_cast<__hip_bfloat162*>(&h1u[ms]);
#pragma unroll
          for (int r = 0; r < 4; ++r) {
            __hip_bfloat162 x = *reinterpret_cast<__hip_bfloat162*>(&hv2.u[r]);
            __hip_bfloat162 y = __hmul2(x, hb);
            av.u[r] = *reinterpret_cast<uint_t*>(&y);
          }
          acc[ms][0] = __builtin_amdgcn_mfma_f32_32x32x16_bf16(av.v, b0, acc[ms][0], 0, 0, 0);
          acc[ms][1] = __builtin_amdgcn_mfma_f32_32x32x16_bf16(av.v, b1, acc[ms][1], 0, 0, 0);
        }
      }
    } else if (i == 128) {
      // A-fragment = h1 directly (linear U1 term)
#pragma unroll
      for (int c = 0; c < 8; ++c) {
        bf16x8 b0 = *reinterpret_cast<const bf16x8*>(&bsh[(nbase_l + l31) * 136 + c * 16 + oct * 8]);
        bf16x8 b1 = *reinterpret_cast<const bf16x8*>(&bsh[(nbase_l + 32 + l31) * 136 + c * 16 + oct * 8]);
#pragma unroll
        for (int ms = 0; ms < 2; ++ms) {
          bf16x8 a = *reinterpret_cast<const bf16x8*>(
              h1bf + (size_t)(mbase + ms * 32 + l31) * HD + c * 16 + oct * 8);
          acc[ms][0] = __builtin_amdgcn_mfma_f32_32x32x16_bf16(a, b0, acc[ms][0], 0, 0, 0);
          acc[ms][1] = __builtin_amdgcn_mfma_f32_32x32x16_bf16(a, b1, acc[ms][1], 0, 0, 0);
        }
      }
    } else {
      // A-fragment = h2 (linear U2 term), already resident
#pragma unroll
      for (int c = 0; c < 8; ++c) {
        bf16x8 b0 = *reinterpret_cast<const bf16x8*>(&bsh[(nbase_l + l31) * 136 + c * 16 + oct * 8]);
        bf16x8 b1 = *reinterpret_cast<const bf16x8*>(&bsh[(nbase_l + 32 + l31) * 136 + c * 16 + oct * 8]);
#pragma unroll
        for (int ms = 0; ms < 2; ++ms) {
          acc[ms][0] = __builtin_amdgcn_mfma_f32_32x32x16_bf16(h2f[ms][c], b0, acc[ms][0], 0, 0, 0);
          acc[ms][1] = __builtin_amdgcn_mfma_f32_32x32x16_bf16(h2f[ms][c], b1, acc[ms][1], 0, 0, 0);
        }
      }
    }
    __syncthreads();
  }

  // epilogue: bias + store. C/D: col = lane&31, row = (reg&3) + 8*(reg>>2) + 4*oct
#pragma unroll
  for (int ns = 0; ns < 2; ++ns) {
    int col = n0 + nbase_l + ns * 32 + l31;
    float bias = u2b[col];
#pragma unroll
    for (int ms = 0; ms < 2; ++ms) {
#pragma unroll
      for (int r = 0; r < 16; ++r) {
        int row = (r & 3) + 8 * (r >> 2) + 4 * oct;
        int m = mbase + ms * 32 + row;
        out[(size_t)m * NOUT + col] = acc[ms][ns][r] + bias;
      }
    }
  }
}

extern "C" void kernel_launch(void* const* d_in, const int* in_sizes, int n_in,
                              void* d_out, int out_size, void* d_ws, size_t ws_size,
                              hipStream_t stream) {
  const float* nh  = (const float*)d_in[0];   // (16384, 2, 128)
  const float* A   = (const float*)d_in[1];   // (128, 128, 384)
  const float* U1  = (const float*)d_in[2];   // (384, 128)
  const float* U2  = (const float*)d_in[3];   // (384, 128)
  const float* U2b = (const float*)d_in[4];   // (384,)

  char* ws = (char*)d_ws;
  ushort_t* Bt   = (ushort_t*)(ws);                 // 384*16640*2  = 12,779,520
  ushort_t* h1bf = (ushort_t*)(ws + 12779520);      // 16384*128*2 =  4,194,304
  ushort_t* h2bf = (ushort_t*)(ws + 16973824);      //               4,194,304
  ushort_t* h1t  = (ushort_t*)(ws + 21168128);      //               4,194,304

  prep_bt<<<dim3(256, 6), 256, 0, stream>>>(A, Bt);
  prep_u<<<dim3(192), 256, 0, stream>>>(U1, U2, Bt);
  prep_h<<<dim3(256, 2), 256, 0, stream>>>(nh, h1bf, h2bf, h1t);
  gemm_kernel<<<dim3(384), 256, 0, stream>>>(Bt, h1bf, h2bf, h1t, U2b, (float*)d_out);
}

// Round 2
// 714.592 us; speedup vs baseline: 1.0345x; 1.0345x over previous
//
#include <hip/hip_runtime.h>
#include <hip/hip_bf16.h>

typedef __attribute__((ext_vector_type(8))) short bf16x8;
typedef __attribute__((ext_vector_type(16))) float f32x16;
typedef __attribute__((ext_vector_type(4))) unsigned int uint4v;
typedef unsigned short ushort_t;
typedef unsigned int uint_t;

#define N_NODES 16384
#define HD 128
#define NOUT 384
#define BT_K 16640            // 16384 + 128 + 128

static __device__ __forceinline__ ushort_t f2bf(float f) {
  __hip_bfloat16 b = __float2bfloat16(f);
  return *reinterpret_cast<ushort_t*>(&b);
}

// ---------------- prep 1: A (16384 x 384 f32, k-major) -> Bt (384 x 16640 bf16) ----------------
__global__ void prep_bt(const float* __restrict__ A, ushort_t* __restrict__ Bt) {
  __shared__ float sm[64][65];
  const int kt = blockIdx.x;          // 0..255
  const int nt = blockIdx.y;          // 0..5
  const int t = threadIdx.x;
  const int tx = t & 63, ty = t >> 6;
  const int k0 = kt * 64, n0 = nt * 64;
#pragma unroll
  for (int s = 0; s < 16; ++s) {
    int kk = ty + s * 4;
    sm[kk][tx] = A[(size_t)(k0 + kk) * NOUT + n0 + tx];
  }
  __syncthreads();
#pragma unroll
  for (int s = 0; s < 16; ++s) {
    int nn = ty + s * 4;
    Bt[(size_t)(n0 + nn) * BT_K + k0 + tx] = f2bf(sm[tx][nn]);
  }
}

// ---------------- prep 2: U1,U2 (384x128) appended to Bt rows ----------------
__global__ void prep_u(const float* __restrict__ U1, const float* __restrict__ U2,
                       ushort_t* __restrict__ Bt) {
  int idx = blockIdx.x * 256 + threadIdx.x;   // 0..49151
  if (idx < NOUT * HD) {
    int n = idx >> 7, i = idx & 127;
    Bt[(size_t)n * BT_K + 16384 + i] = f2bf(U1[idx]);
    Bt[(size_t)n * BT_K + 16512 + i] = f2bf(U2[idx]);
  }
}

// ---------------- prep 3: neighbour_h -> h1_bf, h2_bf (m-major), h1t (i-major) ----------------
__global__ void prep_h(const float* __restrict__ nh, ushort_t* __restrict__ h1,
                       ushort_t* __restrict__ h2, ushort_t* __restrict__ h1t) {
  __shared__ float sm[64][65];
  const int mt = blockIdx.x;          // 0..255
  const int jt = blockIdx.y;          // 0..1
  const int t = threadIdx.x;
  const int tx = t & 63, ty = t >> 6;
  const int m0 = mt * 64, j0 = jt * 64;
#pragma unroll
  for (int s = 0; s < 16; ++s) {
    int mm = ty + s * 4;
    float f1 = nh[(size_t)(m0 + mm) * 256 + j0 + tx];
    float f2 = nh[(size_t)(m0 + mm) * 256 + 128 + j0 + tx];
    h1[(size_t)(m0 + mm) * HD + j0 + tx] = f2bf(f1);
    h2[(size_t)(m0 + mm) * HD + j0 + tx] = f2bf(f2);
    sm[mm][tx] = f1;
  }
  __syncthreads();
#pragma unroll
  for (int s = 0; s < 16; ++s) {
    int jj = ty + s * 4;
    h1t[(size_t)(j0 + jj) * N_NODES + m0 + tx] = f2bf(sm[tx][jj]);
  }
}

// ---------------- main GEMM: out[m][n] = sum_k X[m,k] * Bt[n,k] (+bias) ----------------
// X[m, i*128+j] = h1[m,i]*h2[m,j] for i<128; X[m,16384+i]=h1[m,i]; X[m,16512+j]=h2[m,j]
__global__ __launch_bounds__(256, 2)
void gemm_kernel(const ushort_t* __restrict__ Bt, const ushort_t* __restrict__ h1bf,
                 const ushort_t* __restrict__ h2bf, const ushort_t* __restrict__ h1t,
                 const float* __restrict__ u2b, float* __restrict__ out) {
  __shared__ short bsh[128 * 136];   // B tile [n][k], padded stride 136 (conflict-free)
  const int tid = threadIdx.x;
  const int bid = blockIdx.x;
  const int Nt = bid % 3, Mt = bid / 3;
  const int n0 = Nt * 128, m0 = Mt * 128;
  const int lane = tid & 63, wv = tid >> 6;
  const int l31 = lane & 31, oct = lane >> 5;
  const int wm = wv >> 1, wn = wv & 1;           // 2x2 wave grid
  const int mbase = m0 + wm * 64;
  const int nbase_l = wn * 64;

  // resident h2 A-fragments as raw uints: rows mbase+ms*32+l31, k = c*16 + oct*8 + [0..8)
  // h2u[ms][c] holds 8 bf16 (4 uints)
  uint4v h2u[2][8];
#pragma unroll
  for (int ms = 0; ms < 2; ++ms) {
    const ushort_t* hp = h2bf + (size_t)(mbase + ms * 32 + l31) * HD + oct * 8;
#pragma unroll
    for (int c = 0; c < 8; ++c)
      h2u[ms][c] = *reinterpret_cast<const uint4v*>(hp + c * 16);
  }

  f32x16 acc[2][2];
#pragma unroll
  for (int ms = 0; ms < 2; ++ms)
#pragma unroll
    for (int ns = 0; ns < 2; ++ns)
      acc[ms][ns] = (f32x16)(0.0f);

  uint4 breg[8];
  const char* btbase = reinterpret_cast<const char*>(Bt);
  const int prow = (tid >> 4);         // base row within 16-row group
  const int poff = (tid & 15);

  auto load_breg = [&](int i) {
#pragma unroll
    for (int l = 0; l < 8; ++l) {
      int row = prow + 16 * l;
      breg[l] = *reinterpret_cast<const uint4*>(
          btbase + (size_t)(n0 + row) * (BT_K * 2) + (size_t)i * 256 + poff * 16);
    }
  };
  load_breg(0);

  // h1 scalar prefetch pipeline (2 values, one per ms)
  const int hrow0 = mbase + l31;             // ms=0 row
  const int hrow1 = mbase + 32 + l31;        // ms=1 row
  ushort_t hn0 = h1t[hrow0];                 // i=0
  ushort_t hn1 = h1t[hrow1];

  for (int i = 0; i < 130; ++i) {
    // stage prefetched B tile into LDS (padded)
#pragma unroll
    for (int l = 0; l < 8; ++l) {
      int row = prow + 16 * l;
      *reinterpret_cast<uint4*>(&bsh[row * 136 + poff * 8]) = breg[l];
    }
    __syncthreads();
    if (i < 129) load_breg(i + 1);   // prefetch next tile: in flight across compute

    if (i < 128) {
      // convert current h1 scalars, then prefetch next iteration's
      float h1f[2];
      h1f[0] = __uint_as_float((uint_t)hn0 << 16);
      h1f[1] = __uint_as_float((uint_t)hn1 << 16);
      if (i < 127) {
        hn0 = h1t[(size_t)(i + 1) * N_NODES + hrow0];
        hn1 = h1t[(size_t)(i + 1) * N_NODES + hrow1];
      }
#pragma unroll
      for (int c = 0; c < 8; ++c) {
        bf16x8 b0 = *reinterpret_cast<const bf16x8*>(&bsh[(nbase_l + l31) * 136 + c * 16 + oct * 8]);
        bf16x8 b1 = *reinterpret_cast<const bf16x8*>(&bsh[(nbase_l + 32 + l31) * 136 + c * 16 + oct * 8]);
#pragma unroll
        for (int ms = 0; ms < 2; ++ms) {
          // av = bf16(h1f[ms] * h2) via exact f32 muls + high-half pack (v_perm)
          uint4v avu;
#pragma unroll
          for (int r = 0; r < 4; ++r) {
            uint_t u = h2u[ms][c][r];
            float lo = __uint_as_float(u << 16);
            float hi = __uint_as_float(u & 0xffff0000u);
            uint_t plo = __float_as_uint(lo * h1f[ms]);
            uint_t phi = __float_as_uint(hi * h1f[ms]);
            avu[r] = __builtin_amdgcn_perm(phi, plo, 0x07060302u);
          }
          bf16x8 av = __builtin_bit_cast(bf16x8, avu);
          acc[ms][0] = __builtin_amdgcn_mfma_f32_32x32x16_bf16(av, b0, acc[ms][0], 0, 0, 0);
          acc[ms][1] = __builtin_amdgcn_mfma_f32_32x32x16_bf16(av, b1, acc[ms][1], 0, 0, 0);
        }
      }
    } else if (i == 128) {
      // A-fragment = h1 directly (linear U1 term)
#pragma unroll
      for (int c = 0; c < 8; ++c) {
        bf16x8 b0 = *reinterpret_cast<const bf16x8*>(&bsh[(nbase_l + l31) * 136 + c * 16 + oct * 8]);
        bf16x8 b1 = *reinterpret_cast<const bf16x8*>(&bsh[(nbase_l + 32 + l31) * 136 + c * 16 + oct * 8]);
#pragma unroll
        for (int ms = 0; ms < 2; ++ms) {
          bf16x8 a = *reinterpret_cast<const bf16x8*>(
              h1bf + (size_t)(mbase + ms * 32 + l31) * HD + c * 16 + oct * 8);
          acc[ms][0] = __builtin_amdgcn_mfma_f32_32x32x16_bf16(a, b0, acc[ms][0], 0, 0, 0);
          acc[ms][1] = __builtin_amdgcn_mfma_f32_32x32x16_bf16(a, b1, acc[ms][1], 0, 0, 0);
        }
      }
    } else {
      // A-fragment = h2 (linear U2 term), already resident
#pragma unroll
      for (int c = 0; c < 8; ++c) {
        bf16x8 b0 = *reinterpret_cast<const bf16x8*>(&bsh[(nbase_l + l31) * 136 + c * 16 + oct * 8]);
        bf16x8 b1 = *reinterpret_cast<const bf16x8*>(&bsh[(nbase_l + 32 + l31) * 136 + c * 16 + oct * 8]);
#pragma unroll
        for (int ms = 0; ms < 2; ++ms) {
          bf16x8 a = __builtin_bit_cast(bf16x8, h2u[ms][c]);
          acc[ms][0] = __builtin_amdgcn_mfma_f32_32x32x16_bf16(a, b0, acc[ms][0], 0, 0, 0);
          acc[ms][1] = __builtin_amdgcn_mfma_f32_32x32x16_bf16(a, b1, acc[ms][1], 0, 0, 0);
        }
      }
    }
    __syncthreads();
  }

  // epilogue: bias + store. C/D: col = lane&31, row = (reg&3) + 8*(reg>>2) + 4*oct
#pragma unroll
  for (int ns = 0; ns < 2; ++ns) {
    int col = n0 + nbase_l + ns * 32 + l31;
    float bias = u2b[col];
#pragma unroll
    for (int ms = 0; ms < 2; ++ms) {
#pragma unroll
      for (int r = 0; r < 16; ++r) {
        int row = (r & 3) + 8 * (r >> 2) + 4 * oct;
        int m = mbase + ms * 32 + row;
        out[(size_t)m * NOUT + col] = acc[ms][ns][r] + bias;
      }
    }
  }
}

extern "C" void kernel_launch(void* const* d_in, const int* in_sizes, int n_in,
                              void* d_out, int out_size, void* d_ws, size_t ws_size,
                              hipStream_t stream) {
  const float* nh  = (const float*)d_in[0];   // (16384, 2, 128)
  const float* A   = (const float*)d_in[1];   // (128, 128, 384)
  const float* U1  = (const float*)d_in[2];   // (384, 128)
  const float* U2  = (const float*)d_in[3];   // (384, 128)
  const float* U2b = (const float*)d_in[4];   // (384,)

  char* ws = (char*)d_ws;
  ushort_t* Bt   = (ushort_t*)(ws);                 // 384*16640*2  = 12,779,520
  ushort_t* h1bf = (ushort_t*)(ws + 12779520);      // 16384*128*2 =  4,194,304
  ushort_t* h2bf = (ushort_t*)(ws + 16973824);      //               4,194,304
  ushort_t* h1t  = (ushort_t*)(ws + 21168128);      //               4,194,304

  prep_bt<<<dim3(256, 6), 256, 0, stream>>>(A, Bt);
  prep_u<<<dim3(192), 256, 0, stream>>>(U1, U2, Bt);
  prep_h<<<dim3(256, 2), 256, 0, stream>>>(nh, h1bf, h2bf, h1t);
  gemm_kernel<<<dim3(384), 256, 0, stream>>>(Bt, h1bf, h2bf, h1t, U2b, (float*)d_out);
}